// Round 1
// baseline (202.802 us; speedup 1.0000x reference)
//
#include <hip/hip_runtime.h>
#include <hip/hip_bf16.h>

typedef __bf16 bf16;
typedef __attribute__((ext_vector_type(4)))  __bf16 bf16x4;
typedef __attribute__((ext_vector_type(8)))  __bf16 bf16x8;
typedef __attribute__((ext_vector_type(16))) float  f32x16;
typedef __attribute__((ext_vector_type(4)))  float  f32x4;

#define B_   512
#define NC_  512
#define K_   4
#define S_   8
#define H_   128
#define D_   64

#define SEGS 2
#define ITEMS_PER_BLOCK (B_ / SEGS)              // 256
#define CHUNK_ITEMS 16
#define CHUNK_ROWS  (CHUNK_ITEMS * K_)           // 64
#define NCHUNK (ITEMS_PER_BLOCK / CHUNK_ITEMS)   // 16

// LDS strides in elements; odd dword counts -> <=2-way bank aliasing
#define A1S 68    // one-hot tile [64][68] bf16 (row = 136 B, 8B-aligned)
#define A2S 132   // h tile      [64][132] bf16 (row = 264 B, 8B-aligned)
#define LGS 17    // logits      [64][17]  f32 (overlays A1)

static __device__ __forceinline__ bf16x8 ld8(const bf16* p) {
    bf16x4 lo = *(const bf16x4*)p;
    bf16x4 hi = *(const bf16x4*)(p + 4);
    return __builtin_shufflevector(lo, hi, 0, 1, 2, 3, 4, 5, 6, 7);
}

__global__ __launch_bounds__(256, 2)
void jt_mlp_kernel(const int*   __restrict__ x,
                   const float* __restrict__ W1g, const float* __restrict__ b1g,
                   const float* __restrict__ W2g, const float* __restrict__ b2g,
                   const float* __restrict__ W3g, const float* __restrict__ b3g,
                   float* __restrict__ out)
{
    __shared__ __align__(16) bf16 A1[CHUNK_ROWS * A1S];   // 8704 B (logits overlay)
    __shared__ __align__(16) bf16 A2[CHUNK_ROWS * A2S];   // 17408 B
    float* LG = (float*)A1;

    const int tid  = threadIdx.x;
    const int lane = tid & 63;
    const int w    = tid >> 6;     // wave 0..3: owns H-columns [32w, 32w+32)
    const int l31  = lane & 31;
    const int lhi  = lane >> 5;    // 0/1
    const int l15  = lane & 15;
    const int lq   = lane >> 4;    // 0..3

    const int n     = blockIdx.x >> 1;   // clique
    const int seg   = blockIdx.x & 1;
    const int bbase = seg * ITEMS_PER_BLOCK;

    const float* W1p = W1g + (size_t)n * (D_ * H_);
    const float* W2p = W2g + (size_t)n * (H_ * H_);
    const float* W3p = W3g + (size_t)n * (H_ * S_);

    const int colw = w * 32 + l31;       // this lane's output column for L1/L2

    // ---- preload all weight B-fragments into registers (once per block) ----
    // 32x32x16 B layout: lane holds B[k=(lane>>5)*8+j][ncol=lane&31]
    bf16x8 w1f[4];
#pragma unroll
    for (int kt = 0; kt < 4; ++kt)
#pragma unroll
        for (int j = 0; j < 8; ++j) {
            int k = kt * 16 + lhi * 8 + j;
            w1f[kt][j] = (bf16)W1p[k * H_ + colw];
        }
    bf16x8 w2f[8];
#pragma unroll
    for (int kt = 0; kt < 8; ++kt)
#pragma unroll
        for (int j = 0; j < 8; ++j) {
            int k = kt * 16 + lhi * 8 + j;
            w2f[kt][j] = (bf16)W2p[k * H_ + colw];
        }
    // 16x16x32 B layout: lane holds B[k=(lane>>4)*8+j][ncol=lane&15]; pad cols 8..15 with 0
    bf16x8 w3f[4];
#pragma unroll
    for (int kt = 0; kt < 4; ++kt)
#pragma unroll
        for (int j = 0; j < 8; ++j) {
            int k = kt * 32 + lq * 8 + j;
            w3f[kt][j] = (l15 < S_) ? (bf16)W3p[k * S_ + l15] : (bf16)0.0f;
        }

    const float b1v = b1g[n * H_ + colw];
    const float b2v = b2g[n * H_ + colw];
    float b3v[8];
#pragma unroll
    for (int s = 0; s < 8; ++s) b3v[s] = b3g[n * S_ + s];

    for (int c = 0; c < NCHUNK; ++c) {
        __syncthreads();  // prev chunk: softmax reads of LG(A1) + L3 reads of A2 done
        // ---- zero one-hot tile (8704 B = 544 * 16 B) ----
        for (int i = tid; i < (CHUNK_ROWS * A1S) / 8; i += 256)
            ((uint4*)A1)[i] = make_uint4(0, 0, 0, 0);
        __syncthreads();
        // ---- scatter ones: row r = item*4 + k ----
        if (tid < CHUNK_ITEMS) {
            const int item = tid;
            const int b = bbase + c * CHUNK_ITEMS + item;
            const int* xb = x + (size_t)b * (NC_ * K_);
            const int4 xo = *(const int4*)(xb + n * K_);
            const int xoA[4] = {xo.x, xo.y, xo.z, xo.w};
            const int r0 = item * K_;
            const bf16 one = (bf16)1.0f;
            if (n > 0) {                    // parent separator one-hots (cols 0..31)
                const int4 xp = *(const int4*)(xb + (n - 1) * K_);
                const int xpA[4] = {xp.x, xp.y, xp.z, xp.w};
#pragma unroll
                for (int i4 = 0; i4 < 4; ++i4) {
                    const int colp = i4 * 8 + xpA[i4];
#pragma unroll
                    for (int k = 0; k < 4; ++k) A1[(r0 + k) * A1S + colp] = one;
                }
            }
#pragma unroll
            for (int j = 0; j < 3; ++j) {   // autoregressive prefix (cols 32..63)
                const int colq = 32 + j * 8 + xoA[j];
#pragma unroll
                for (int k = 0; k < 4; ++k)
                    if (k > j) A1[(r0 + k) * A1S + colq] = one;
            }
        }
        __syncthreads();

        // ---------- layer 1: [64x64 one-hot] @ W1 -> h1 [64x128] ----------
        f32x16 acc0, acc1;
#pragma unroll
        for (int i = 0; i < 16; ++i) { acc0[i] = 0.f; acc1[i] = 0.f; }
#pragma unroll
        for (int kt = 0; kt < 4; ++kt) {
            bf16x8 a0 = ld8(&A1[(l31) * A1S + kt * 16 + lhi * 8]);
            bf16x8 a1 = ld8(&A1[(32 + l31) * A1S + kt * 16 + lhi * 8]);
            acc0 = __builtin_amdgcn_mfma_f32_32x32x16_bf16(a0, w1f[kt], acc0, 0, 0, 0);
            acc1 = __builtin_amdgcn_mfma_f32_32x32x16_bf16(a1, w1f[kt], acc1, 0, 0, 0);
        }
        // C/D 32x32: col=lane&31, row=(r&3)+8*(r>>2)+4*(lane>>5)
#pragma unroll
        for (int r = 0; r < 16; ++r) {
            const int row = (r & 3) + 8 * (r >> 2) + 4 * lhi;
            float v0 = fmaxf(acc0[r] + b1v, 0.f);
            float v1 = fmaxf(acc1[r] + b1v, 0.f);
            A2[row * A2S + colw]        = (bf16)v0;
            A2[(row + 32) * A2S + colw] = (bf16)v1;
        }
        __syncthreads();

        // ---------- layer 2: h1 @ W2 -> h2 [64x128] ----------
#pragma unroll
        for (int i = 0; i < 16; ++i) { acc0[i] = 0.f; acc1[i] = 0.f; }
#pragma unroll
        for (int kt = 0; kt < 8; ++kt) {
            bf16x8 a0 = ld8(&A2[(l31) * A2S + kt * 16 + lhi * 8]);
            bf16x8 a1 = ld8(&A2[(32 + l31) * A2S + kt * 16 + lhi * 8]);
            acc0 = __builtin_amdgcn_mfma_f32_32x32x16_bf16(a0, w2f[kt], acc0, 0, 0, 0);
            acc1 = __builtin_amdgcn_mfma_f32_32x32x16_bf16(a1, w2f[kt], acc1, 0, 0, 0);
        }
        __syncthreads();   // all waves done reading h1 before in-place overwrite
#pragma unroll
        for (int r = 0; r < 16; ++r) {
            const int row = (r & 3) + 8 * (r >> 2) + 4 * lhi;
            float v0 = fmaxf(acc0[r] + b2v, 0.f);
            float v1 = fmaxf(acc1[r] + b2v, 0.f);
            A2[row * A2S + colw]        = (bf16)v0;
            A2[(row + 32) * A2S + colw] = (bf16)v1;
        }
        __syncthreads();

        // ---------- layer 3 (16x16x32): wave w -> rows [16w,16w+16), cols 0..15 ----------
        f32x4 acc3;
#pragma unroll
        for (int i = 0; i < 4; ++i) acc3[i] = 0.f;
#pragma unroll
        for (int kt = 0; kt < 4; ++kt) {
            bf16x8 a = ld8(&A2[(w * 16 + l15) * A2S + kt * 32 + lq * 8]);
            acc3 = __builtin_amdgcn_mfma_f32_16x16x32_bf16(a, w3f[kt], acc3, 0, 0, 0);
        }
        // C/D 16x16: col=lane&15, row=(lane>>4)*4+reg
#pragma unroll
        for (int r = 0; r < 4; ++r) {
            const int row = w * 16 + lq * 4 + r;
            LG[row * LGS + l15] = acc3[r];
        }
        __syncthreads();

        // ---------- log-softmax + gather + sum over K ----------
        if (tid < CHUNK_ROWS) {
            const int row  = tid;
            const int item = row >> 2;
            const int k    = row & 3;
            const int b    = bbase + c * CHUNK_ITEMS + item;
            float m = -1e30f;
#pragma unroll
            for (int s = 0; s < 8; ++s)
                m = fmaxf(m, LG[row * LGS + s] + b3v[s]);
            float sum = 0.f;
#pragma unroll
            for (int s = 0; s < 8; ++s)
                sum += __expf(LG[row * LGS + s] + b3v[s] - m);
            const int xs = x[(size_t)b * (NC_ * K_) + n * K_ + k];
            const float lobs = LG[row * LGS + xs] + b3g[n * S_ + xs];
            float lp = lobs - m - __logf(sum);
            lp += __shfl_down(lp, 1);   // rows of one item are 4 consecutive lanes
            lp += __shfl_down(lp, 2);
            if (k == 0) out[(size_t)b * NC_ + n] = lp;
        }
    }
}

extern "C" void kernel_launch(void* const* d_in, const int* in_sizes, int n_in,
                              void* d_out, int out_size, void* d_ws, size_t ws_size,
                              hipStream_t stream) {
    const int*   x  = (const int*)d_in[0];
    const float* W1 = (const float*)d_in[1];
    const float* b1 = (const float*)d_in[2];
    const float* W2 = (const float*)d_in[3];
    const float* b2 = (const float*)d_in[4];
    const float* W3 = (const float*)d_in[5];
    const float* b3 = (const float*)d_in[6];
    float* out = (float*)d_out;
    dim3 grid(NC_ * SEGS);   // 1024 blocks: 2 per clique
    jt_mlp_kernel<<<grid, 256, 0, stream>>>(x, W1, b1, W2, b2, W3, b3, out);
}

// Round 2
// 196.750 us; speedup vs baseline: 1.0308x; 1.0308x over previous
//
#include <hip/hip_runtime.h>
#include <hip/hip_bf16.h>

typedef __bf16 bf16;
typedef __attribute__((ext_vector_type(4)))  __bf16 bf16x4;
typedef __attribute__((ext_vector_type(8)))  __bf16 bf16x8;
typedef __attribute__((ext_vector_type(16))) float  f32x16;
typedef __attribute__((ext_vector_type(4)))  float  f32x4;

#define B_   512
#define NC_  512
#define K_   4
#define S_   8
#define H_   128
#define D_   64

#define SEGS 4
#define ITEMS_PER_BLOCK (B_ / SEGS)              // 128
#define CHUNK_ITEMS 16
#define CHUNK_ROWS  (CHUNK_ITEMS * K_)           // 64
#define NCHUNK (ITEMS_PER_BLOCK / CHUNK_ITEMS)   // 8

// Row strides chosen so rows are 16B-aligned AND all access patterns hit the
// 8-accesses/bank LDS minimum (b64 stores: lhi-halves land on disjoint bank pairs).
#define A1S 72    // one-hot tile [64][72] bf16, 144 B rows
#define A2S 136   // h tile      [64][136] bf16, 272 B rows

__global__ __launch_bounds__(256, 3)
void jt_mlp_kernel(const int*   __restrict__ x,
                   const float* __restrict__ W1g, const float* __restrict__ b1g,
                   const float* __restrict__ W2g, const float* __restrict__ b2g,
                   const float* __restrict__ W3g, const float* __restrict__ b3g,
                   float* __restrict__ out)
{
    __shared__ __align__(16) bf16 A1[CHUNK_ROWS * A1S];   // 9216 B
    __shared__ __align__(16) bf16 A2[CHUNK_ROWS * A2S];   // 17408 B

    const int tid  = threadIdx.x;
    const int lane = tid & 63;
    const int w    = tid >> 6;     // wave 0..3
    const int l31  = lane & 31;
    const int lhi  = lane >> 5;    // 0/1
    const int l15  = lane & 15;
    const int lq   = lane >> 4;    // 0..3

    const int n     = blockIdx.x >> 2;   // clique
    const int seg   = blockIdx.x & 3;
    const int bbase = seg * ITEMS_PER_BLOCK;

    const float* W1p = W1g + (size_t)n * (D_ * H_);
    const float* W2p = W2g + (size_t)n * (H_ * H_);
    const float* W3p = W3g + (size_t)n * (H_ * S_);

    const int colw = w * 32 + l31;       // lane's weight column for L1/L2 A-frags

    // ---- weight fragments (A-operand; identical bytes to B-layout) ----
    // 32x32x16 A layout: lane holds A[m=lane&31][k=(lane>>5)*8+j] = W[k][colw]
    bf16x8 w1f[4];
#pragma unroll
    for (int kt = 0; kt < 4; ++kt)
#pragma unroll
        for (int j = 0; j < 8; ++j)
            w1f[kt][j] = (bf16)W1p[(kt * 16 + lhi * 8 + j) * H_ + colw];
    bf16x8 w2f[8];
#pragma unroll
    for (int kt = 0; kt < 8; ++kt)
#pragma unroll
        for (int j = 0; j < 8; ++j)
            w2f[kt][j] = (bf16)W2p[(kt * 16 + lhi * 8 + j) * H_ + colw];
    // 16x16x32 A layout: lane holds A[m=lane&15][k=(lane>>4)*8+j] = W3[k][l15]
    bf16x8 w3f[4];
#pragma unroll
    for (int kt = 0; kt < 4; ++kt)
#pragma unroll
        for (int j = 0; j < 8; ++j)
            w3f[kt][j] = (l15 < S_) ? (bf16)W3p[(kt * 32 + lq * 8 + j) * S_ + l15]
                                    : (bf16)0.0f;

    // ---- biases: per-lane m-cols are w*32 + 4*lhi + 8g + i (g,i in 0..3) ----
    float4 b1q[4], b2q[4];
#pragma unroll
    for (int g = 0; g < 4; ++g) {
        b1q[g] = *(const float4*)(b1g + n * H_ + w * 32 + 4 * lhi + 8 * g);
        b2q[g] = *(const float4*)(b2g + n * H_ + w * 32 + 4 * lhi + 8 * g);
    }
    float4 b3q = (lq < 2) ? *(const float4*)(b3g + n * S_ + lq * 4)
                          : make_float4(0.f, 0.f, 0.f, 0.f);

    // build-phase mapping: wave = 16-col segment, lane = row
    const int brow  = lane;          // 0..63
    const int bitem = brow >> 2;
    const int bk    = brow & 3;

    for (int c = 0; c < NCHUNK; ++c) {
        // ---------- build one-hot tile (all 256 threads, b128 stores) ----------
        {
            const int b = bbase + c * CHUNK_ITEMS + bitem;
            const int* xb = x + (size_t)b * (NC_ * K_);
            bf16x8 v0, v1;
            const bf16 one = (bf16)1.0f, zero = (bf16)0.0f;
            if (w < 2) {            // parent one-hot halves (cols 0..31)
                int p0 = -1, p1 = -1;
                if (n > 0) {
                    const int4 xp = *(const int4*)(xb + (n - 1) * K_);
                    p0 = (w == 0) ? xp.x : xp.z;
                    p1 = (w == 0) ? xp.y : xp.w;
                }
#pragma unroll
                for (int i = 0; i < 8; ++i) {
                    v0[i] = (p0 == i) ? one : zero;
                    v1[i] = (p1 == i) ? one : zero;
                }
            } else {                // autoregressive prefix (cols 32..63)
                const int4 xo = *(const int4*)(xb + n * K_);
                const int j0 = (w - 2) * 2, j1 = j0 + 1;
                const int q0 = (w == 2) ? xo.x : xo.z;
                const int q1 = (w == 2) ? xo.y : xo.w;
                const bool e0 = bk > j0, e1 = bk > j1;
#pragma unroll
                for (int i = 0; i < 8; ++i) {
                    v0[i] = (e0 && q0 == i) ? one : zero;
                    v1[i] = (e1 && q1 == i) ? one : zero;
                }
            }
            *(bf16x8*)&A1[brow * A1S + w * 16]     = v0;
            *(bf16x8*)&A1[brow * A1S + w * 16 + 8] = v1;
        }
        __syncthreads();   // also covers prev-chunk L3 reads of A2 vs L1 writes

        // ---------- layer 1: D = W1^T · onehot^T (lane=row, regs=H-cols) ----------
        f32x16 acc0, acc1;
#pragma unroll
        for (int r = 0; r < 16; ++r) {
            const float bv = ((const float*)&b1q[r >> 2])[r & 3];
            acc0[r] = bv; acc1[r] = bv;
        }
#pragma unroll
        for (int kt = 0; kt < 4; ++kt) {
            bf16x8 x0 = *(const bf16x8*)&A1[l31 * A1S + kt * 16 + lhi * 8];
            bf16x8 x1 = *(const bf16x8*)&A1[(32 + l31) * A1S + kt * 16 + lhi * 8];
            acc0 = __builtin_amdgcn_mfma_f32_32x32x16_bf16(w1f[kt], x0, acc0, 0, 0, 0);
            acc1 = __builtin_amdgcn_mfma_f32_32x32x16_bf16(w1f[kt], x1, acc1, 0, 0, 0);
        }
        // D: col(lane&31)=batch-row, row-reg m=(r&3)+8*(r>>2)+4*lhi -> 4-col packs
#pragma unroll
        for (int g = 0; g < 4; ++g) {
            bf16x4 s0, s1;
#pragma unroll
            for (int i = 0; i < 4; ++i) {
                s0[i] = (bf16)fmaxf(acc0[4 * g + i], 0.f);
                s1[i] = (bf16)fmaxf(acc1[4 * g + i], 0.f);
            }
            const int col = w * 32 + 4 * lhi + 8 * g;
            *(bf16x4*)&A2[l31 * A2S + col]        = s0;
            *(bf16x4*)&A2[(32 + l31) * A2S + col] = s1;
        }
        __syncthreads();

        // ---------- layer 2: D = W2^T · h1^T ----------
#pragma unroll
        for (int r = 0; r < 16; ++r) {
            const float bv = ((const float*)&b2q[r >> 2])[r & 3];
            acc0[r] = bv; acc1[r] = bv;
        }
#pragma unroll
        for (int kt = 0; kt < 8; ++kt) {
            bf16x8 x0 = *(const bf16x8*)&A2[l31 * A2S + kt * 16 + lhi * 8];
            bf16x8 x1 = *(const bf16x8*)&A2[(32 + l31) * A2S + kt * 16 + lhi * 8];
            acc0 = __builtin_amdgcn_mfma_f32_32x32x16_bf16(w2f[kt], x0, acc0, 0, 0, 0);
            acc1 = __builtin_amdgcn_mfma_f32_32x32x16_bf16(w2f[kt], x1, acc1, 0, 0, 0);
        }
        __syncthreads();   // all reads of h1 done before in-place overwrite
#pragma unroll
        for (int g = 0; g < 4; ++g) {
            bf16x4 s0, s1;
#pragma unroll
            for (int i = 0; i < 4; ++i) {
                s0[i] = (bf16)fmaxf(acc0[4 * g + i], 0.f);
                s1[i] = (bf16)fmaxf(acc1[4 * g + i], 0.f);
            }
            const int col = w * 32 + 4 * lhi + 8 * g;
            *(bf16x4*)&A2[l31 * A2S + col]        = s0;
            *(bf16x4*)&A2[(32 + l31) * A2S + col] = s1;
        }
        __syncthreads();

        // ---------- layer 3: D = W3^T · h2^T ; wave w -> rows w*16..w*16+15 ----------
        f32x4 acc3;
#pragma unroll
        for (int r = 0; r < 4; ++r)
            acc3[r] = ((const float*)&b3q)[r];
#pragma unroll
        for (int kt = 0; kt < 4; ++kt) {
            bf16x8 hx = *(const bf16x8*)&A2[(w * 16 + l15) * A2S + kt * 32 + lq * 8];
            acc3 = __builtin_amdgcn_mfma_f32_16x16x32_bf16(w3f[kt], hx, acc3, 0, 0, 0);
        }
        // D: col(lane&15)=batch-row(w*16+l15), row m = lq*4+r = state s.
        // Lane lq=0 holds s=0..3, lq=1 holds s=4..7 (lq>=2: zeros, unused).

        // ---------- register log-softmax + gather + sum over K ----------
        {
            const int row  = w * 16 + l15;
            const int item = row >> 2;
            const int k    = row & 3;
            const int b    = bbase + c * CHUNK_ITEMS + item;
            const int xs   = x[(size_t)b * (NC_ * K_) + n * K_ + k];

            float lm = fmaxf(fmaxf(acc3[0], acc3[1]), fmaxf(acc3[2], acc3[3]));
            const float m_ = fmaxf(lm, __shfl_xor(lm, 16));
            float ls = __expf(acc3[0] - m_) + __expf(acc3[1] - m_) +
                       __expf(acc3[2] - m_) + __expf(acc3[3] - m_);
            const float sum = ls + __shfl_xor(ls, 16);

            const float cand = ((const float*)&acc3)[xs & 3];
            const float partner = __shfl_xor(cand, 16);
            const float obs = ((xs >> 2) == lq) ? cand : partner;

            float lp = obs - m_ - __logf(sum);
            lp += __shfl_xor(lp, 1);
            lp += __shfl_xor(lp, 2);
            if (lq == 0 && (l15 & 3) == 0)
                out[(size_t)b * NC_ + n] = lp;
        }
        // next iteration's build-barrier also fences L3 A2-reads vs L1 A2-writes
    }
}

extern "C" void kernel_launch(void* const* d_in, const int* in_sizes, int n_in,
                              void* d_out, int out_size, void* d_ws, size_t ws_size,
                              hipStream_t stream) {
    const int*   x  = (const int*)d_in[0];
    const float* W1 = (const float*)d_in[1];
    const float* b1 = (const float*)d_in[2];
    const float* W2 = (const float*)d_in[3];
    const float* b2 = (const float*)d_in[4];
    const float* W3 = (const float*)d_in[5];
    const float* b3 = (const float*)d_in[6];
    float* out = (float*)d_out;
    dim3 grid(NC_ * SEGS);   // 2048 blocks: 4 per clique
    jt_mlp_kernel<<<grid, 256, 0, stream>>>(x, W1, b1, W2, b2, W3, b3, out);
}